// Round 11
// baseline (233.689 us; speedup 1.0000x reference)
//
#include <hip/hip_runtime.h>
#include <math.h>

#define BB 256
#define NN 512
#define DD 6
#define F_IN 62
#define HH 128
#define ND 7
#define TOTAL (BB*NN)     // 131072
#define MAXS 132096       // padded slots: 131072 + 7*127 rounded to 1032*128
#define MAXT 1032         // 128-row tiles
#define STG 132           // epilogue staging row stride (bank-spread)

typedef __bf16 bf16x8 __attribute__((ext_vector_type(8)));
typedef float f32x4 __attribute__((ext_vector_type(4)));

__device__ __forceinline__ unsigned short f2bf(float f) {
    unsigned u = __builtin_bit_cast(unsigned, f);
    u = (u + 0x7FFFu + ((u >> 16) & 1u)) >> 16;
    return (unsigned short)u;
}
__device__ __forceinline__ float lo2f(unsigned x) { return __builtin_bit_cast(float, x << 16); }
__device__ __forceinline__ float hi2f(unsigned x) { return __builtin_bit_cast(float, x & 0xFFFF0000u); }

__device__ __forceinline__ uint4 pack8(const float* s) {
    uint4 r;
    r.x = (unsigned)f2bf(s[0]) | ((unsigned)f2bf(s[1]) << 16);
    r.y = (unsigned)f2bf(s[2]) | ((unsigned)f2bf(s[3]) << 16);
    r.z = (unsigned)f2bf(s[4]) | ((unsigned)f2bf(s[5]) << 16);
    r.w = (unsigned)f2bf(s[6]) | ((unsigned)f2bf(s[7]) << 16);
    return r;
}
__device__ __forceinline__ void unpack_add(float* s, uint4 q) {
    s[0] += lo2f(q.x); s[1] += hi2f(q.x); s[2] += lo2f(q.y); s[3] += hi2f(q.y);
    s[4] += lo2f(q.z); s[5] += hi2f(q.z); s[6] += lo2f(q.w); s[7] += hi2f(q.w);
}
__device__ __forceinline__ void unpack_max(float* s, uint4 q) {
    s[0] = fmaxf(s[0], lo2f(q.x)); s[1] = fmaxf(s[1], hi2f(q.x));
    s[2] = fmaxf(s[2], lo2f(q.y)); s[3] = fmaxf(s[3], hi2f(q.y));
    s[4] = fmaxf(s[4], lo2f(q.z)); s[5] = fmaxf(s[5], hi2f(q.z));
    s[6] = fmaxf(s[6], lo2f(q.w)); s[7] = fmaxf(s[7], hi2f(q.w));
}
__device__ __forceinline__ void rowadd62(float* s, const float* r, int kb) {
    float2 z0 = *(const float2*)(r);     s[0] += z0.x; s[1] += z0.y;
    float2 z1 = *(const float2*)(r + 2); s[2] += z1.x; s[3] += z1.y;
    float2 z2 = *(const float2*)(r + 4); s[4] += z2.x; s[5] += z2.y;
    if (kb < 7) { float2 z3 = *(const float2*)(r + 6); s[6] += z3.x; s[7] += z3.y; }
}

// ---------------- global stable degree sort, buckets padded to 128 ----------------

__global__ __launch_bounds__(512) void k_hist_bd(const int* __restrict__ e,
                                                 int* __restrict__ deg,
                                                 int* __restrict__ cnt) {
    __shared__ unsigned int lh[ND];
    const int b = blockIdx.x;
    const int t = threadIdx.x;
    if (t < ND) lh[t] = 0u;
    __syncthreads();
    int d = 0;
#pragma unroll
    for (int j = 0; j < DD; ++j) d += (e[(b * NN + t) * DD + j] >= 0) ? 1 : 0;
    deg[b * NN + t] = d;
    atomicAdd(&lh[d], 1u);
    __syncthreads();
    if (t < ND) cnt[b * 8 + t] = (int)lh[t];
}

__global__ void k_scan_bd(const int* __restrict__ cnt,
                          int* __restrict__ base_bd,
                          int* __restrict__ tdeg) {
    __shared__ int gb[8];
    const int t = threadIdx.x;
    if (t == 0) {
        int tot[ND];
        for (int d = 0; d < ND; ++d) tot[d] = 0;
        for (int b = 0; b < BB; ++b)
            for (int d = 0; d < ND; ++d) tot[d] += cnt[b * 8 + d];
        int acc = 0;
        for (int d = 0; d < ND; ++d) { gb[d] = acc; acc += (tot[d] + 127) & ~127; }
        gb[7] = acc;
        for (int d = 0; d < ND; ++d) {
            int r = gb[d];
            for (int b = 0; b < BB; ++b) { base_bd[b * 8 + d] = r; r += cnt[b * 8 + d]; }
        }
    }
    __syncthreads();
    for (int i = t; i < MAXT; i += 256) {
        int s = i * 128;
        int dd = 0;
        for (int d = ND - 1; d >= 0; --d) if (s >= gb[d]) { dd = d; break; }
        tdeg[i] = (s < gb[7]) ? dd : 0;
    }
}

__global__ __launch_bounds__(512) void k_init_order(int* __restrict__ order) {
    order[blockIdx.x * 512 + threadIdx.x] = -1;
}

__global__ __launch_bounds__(512) void k_scatter(const int* __restrict__ deg,
                                                 const int* __restrict__ base_bd,
                                                 int* __restrict__ order,
                                                 int* __restrict__ inv) {
    __shared__ unsigned int rk[ND];
    const int b = blockIdx.x;
    const int t = threadIdx.x;
    if (t < ND) rk[t] = 0u;
    __syncthreads();
    const int u = b * NN + t;
    const int d = deg[u];
    unsigned r = atomicAdd(&rk[d], 1u);
    const int slot = base_bd[b * 8 + d] + (int)r;
    order[slot] = u;
    inv[u] = slot;
}

// ---------------- prep: W [ND][F][HH] f32 -> WT [ND][HH][K] bf16 (K-contig, pad) ----------------

__global__ void k_prep_wt(const float* __restrict__ W, unsigned short* __restrict__ WT,
                          int F, int K) {
    int n = blockIdx.x;   // 0..127
    int d = blockIdx.y;   // 0..6
    for (int k = threadIdx.x; k < K; k += 64) {
        float v = (k < F) ? W[((size_t)d * F + k) * HH + n] : 0.f;
        WT[((size_t)d * HH + n) * K + k] = f2bf(v);
    }
}

// ---------------- gather1: S1[slot][0..64) = a[v] + sum(a[nbr]) (sorted layout) ----------------

__global__ __launch_bounds__(512)
void k_gather1(const float* __restrict__ a, const int* __restrict__ e,
               const int* __restrict__ order, unsigned short* __restrict__ S1) {
    const int u = blockIdx.x * 512 + threadIdx.x;   // MAXS*8 threads
    const int slot = u >> 3;
    const int kb = u & 7;
    const int v = order[slot];
    if (v < 0) return;
    const int* ep = e + (size_t)v * DD;
    const int nb = v & ~(NN - 1);
    float s[8] = {0.f, 0.f, 0.f, 0.f, 0.f, 0.f, 0.f, 0.f};
    rowadd62(s, a + (size_t)v * F_IN + kb * 8, kb);
#pragma unroll
    for (int jj = 0; jj < DD; ++jj) {
        int idx = ep[jj];
        if (idx >= 0) rowadd62(s, a + (size_t)(nb + idx) * F_IN + kb * 8, kb);
    }
    *(uint4*)(S1 + (size_t)slot * 64 + kb * 8) = pack8(s);
}

// ---------------- gather2: S2[slot][0..128) = p1[v] + sum(p1[nbr]) (sorted layout) -------------

__global__ __launch_bounds__(512)
void k_gather2(const unsigned short* __restrict__ P1, const int* __restrict__ e,
               const int* __restrict__ order, unsigned short* __restrict__ S2) {
    const int u = blockIdx.x * 512 + threadIdx.x;   // MAXS*16 threads
    const int slot = u >> 4;
    const int kb = u & 15;
    const int v = order[slot];
    if (v < 0) return;
    const int* ep = e + (size_t)v * DD;
    const int nb = v & ~(NN - 1);
    const unsigned short* base = P1 + kb * 8;
    float s[8] = {0.f, 0.f, 0.f, 0.f, 0.f, 0.f, 0.f, 0.f};
    unpack_add(s, *(const uint4*)(base + (size_t)v * HH));
#pragma unroll
    for (int jj = 0; jj < DD; ++jj) {
        int idx = ep[jj];
        if (idx >= 0) unpack_add(s, *(const uint4*)(base + (size_t)(nb + idx) * HH));
    }
    *(uint4*)(S2 + (size_t)slot * HH + kb * 8) = pack8(s);
}

// ---------------- degree-pure 128-row tile GEMM, W[d] staged in LDS ----------------------------
// Block = 1 tile (128 sorted rows x 128 cols), 8 waves; wave w = rows [w*16, w*16+16).
// A-frags read straight from global S (issued before the W barrier -> overlap staging).
// B-frags from XOR-swizzled LDS copy of W[d] (loaded ONCE per block - kills per-wave L2 B-traffic).

template<int KB>   // 8 (K=64) or 16 (K=128)
__global__ __launch_bounds__(512, 4)
void k_gemm_big(const unsigned short* __restrict__ S,
                const unsigned short* __restrict__ WT, const float* __restrict__ bias,
                const int* __restrict__ tdeg, unsigned short* __restrict__ Y) {
    constexpr int K = KB * 8;
    constexpr int KK = KB / 4;
    constexpr int LOGKB = (KB == 16) ? 4 : 3;
    extern __shared__ char smem[];
    unsigned short* Wl  = (unsigned short*)smem;                  // 128 x K, swizzled
    unsigned short* stg = (unsigned short*)(smem + 128 * K * 2);  // 128 x STG

    const int t = threadIdx.x;
    const int l = t & 63;
    const int w = t >> 6;
    const int lr = l & 15;
    const int lq = l >> 4;

    const int tile = blockIdx.x;
    const int d = tdeg[tile];

    // stage W[d] -> LDS (coalesced, XOR-swizzled rows)
    for (int u = t; u < 128 * KB; u += 512) {
        const int row = u >> LOGKB;
        const int kb = u & (KB - 1);
        *(uint4*)&Wl[(row * KB + (kb ^ (row & 7))) * 8] =
            *(const uint4*)(WT + ((size_t)d * HH + row) * K + kb * 8);
    }

    // A fragments straight from global (independent of W staging)
    const unsigned short* sp = S + (size_t)(tile * 128 + w * 16 + lr) * K;
    bf16x8 af[KK];
#pragma unroll
    for (int kk = 0; kk < KK; ++kk)
        af[kk] = *(const bf16x8*)(sp + (lq + 4 * kk) * 8);

    __syncthreads();   // W ready

#pragma unroll
    for (int fr = 0; fr < 8; ++fr) {
        const int col = fr * 16 + lr;
        f32x4 z = {0.f, 0.f, 0.f, 0.f};
#pragma unroll
        for (int kk = 0; kk < KK; ++kk) {
            bf16x8 bfr = *(const bf16x8*)&Wl[(col * KB + ((kk * 4 + lq) ^ (col & 7))) * 8];
            z = __builtin_amdgcn_mfma_f32_16x16x32_bf16(af[kk], bfr, z, 0, 0, 0);
        }
        const float bv = bias[d * HH + col];
#pragma unroll
        for (int r2 = 0; r2 < 4; ++r2) {
            float zz = 1.f / (1.f + __expf(-(z[r2] + bv)));
            stg[(w * 16 + lq * 4 + r2) * STG + col] = f2bf(zz);
        }
    }

    __syncthreads();
    for (int u = t; u < 2048; u += 512) {
        const int n = u >> 4;
        const int c8 = (u & 15) * 8;
        uint4 p = *(const uint4*)&stg[n * STG + c8];
        *(uint4*)&Y[((size_t)tile * 128 + n) * HH + c8] = p;
    }
}

// ---------------- pool1: P[v] = max(h1s[inv[v]], h1s[inv[nbr]]), natural output ----------------

__global__ __launch_bounds__(256) void k_pool_bf(const unsigned short* __restrict__ Xs,
                                                 const int* __restrict__ e,
                                                 const int* __restrict__ inv,
                                                 unsigned short* __restrict__ P) {
    const int t = threadIdx.x;
    const int u = blockIdx.x * 16 + (t >> 4);
    const int c8 = (t & 15) * 8;
    const int nb = u & ~(NN - 1);
    const unsigned short* base = Xs + c8;
    float m[8];
    {
        uint4 p = *(const uint4*)(base + (size_t)inv[u] * HH);
        m[0] = lo2f(p.x); m[1] = hi2f(p.x); m[2] = lo2f(p.y); m[3] = hi2f(p.y);
        m[4] = lo2f(p.z); m[5] = hi2f(p.z); m[6] = lo2f(p.w); m[7] = hi2f(p.w);
    }
#pragma unroll
    for (int jj = 0; jj < DD; ++jj) {
        int idx = e[u * DD + jj];
        if (idx >= 0) unpack_max(m, *(const uint4*)(base + (size_t)inv[nb + idx] * HH));
    }
    *(uint4*)&P[(size_t)u * HH + c8] = pack8(m);
}

// ---------------- final: pool over h2s (via inv) + partial sum (32 blocks/batch) ---------------

__global__ __launch_bounds__(256) void k_pool_sum_part(const unsigned short* __restrict__ Xs,
                                                       const int* __restrict__ e,
                                                       const int* __restrict__ inv,
                                                       float* __restrict__ partial) {
    __shared__ float red[16][HH + 4];
    const int t = threadIdx.x;
    const int b = blockIdx.x >> 5;
    const int chunk = blockIdx.x & 31;
    const int slot = t >> 4;
    const int c8 = (t & 15) * 8;

    const int u = b * NN + chunk * 16 + slot;
    const unsigned short* base = Xs + c8;
    float m[8];
    {
        uint4 p = *(const uint4*)(base + (size_t)inv[u] * HH);
        m[0] = lo2f(p.x); m[1] = hi2f(p.x); m[2] = lo2f(p.y); m[3] = hi2f(p.y);
        m[4] = lo2f(p.z); m[5] = hi2f(p.z); m[6] = lo2f(p.w); m[7] = hi2f(p.w);
    }
#pragma unroll
    for (int jj = 0; jj < DD; ++jj) {
        int idx = e[u * DD + jj];
        if (idx >= 0) unpack_max(m, *(const uint4*)(base + (size_t)inv[b * NN + idx] * HH));
    }
#pragma unroll
    for (int i = 0; i < 8; ++i) red[slot][c8 + i] = m[i];
    __syncthreads();
    if (t < HH) {
        float s = 0.f;
#pragma unroll
        for (int k = 0; k < 16; ++k) s += red[k][t];
        partial[((size_t)b * 32 + chunk) * HH + t] = s;
    }
}

__global__ __launch_bounds__(256) void k_sum_final(const float* __restrict__ partial,
                                                   float* __restrict__ out) {
    int g = blockIdx.x * 256 + threadIdx.x;
    int b = g >> 7;
    int c = g & 127;
    float s = 0.f;
#pragma unroll
    for (int k = 0; k < 32; ++k) s += partial[((size_t)b * 32 + k) * HH + c];
    out[g] = s;
}

// ---------------- launcher ----------------
// ws overlays (SZ = MAXS*128*2 = 33.8 MB):
//   bufA [0,SZ):    h1s (gemm1 out, pool1 in) -> S2 (gather2 out, gemm2 in) -> partial
//   bufB [SZ,2SZ):  S1 (gather1 out, gemm1 in) -> p1 (pool1 out, gather2 in) -> h2s (gemm2 out)
//   meta [2SZ+):    WT0, WT1, order, inv, deg, cnt, base_bd, tdeg   (~70 MB total)

extern "C" void kernel_launch(void* const* d_in, const int* in_sizes, int n_in,
                              void* d_out, int out_size, void* d_ws, size_t ws_size,
                              hipStream_t stream) {
    const float* a  = (const float*)d_in[0];
    const int*   e  = (const int*)d_in[1];
    const float* W0 = (const float*)d_in[2];
    const float* b0 = (const float*)d_in[3];
    const float* W1 = (const float*)d_in[4];
    const float* b1 = (const float*)d_in[5];
    float* out = (float*)d_out;

    char* ws = (char*)d_ws;
    const size_t SZ = (size_t)MAXS * HH * 2;
    unsigned short* bufA = (unsigned short*)ws;
    unsigned short* bufB = (unsigned short*)(ws + SZ);
    float* partial = (float*)bufA;
    char* dp = ws + 2 * SZ;
    unsigned short* WT0 = (unsigned short*)dp;
    unsigned short* WT1 = WT0 + (size_t)ND * HH * 64;
    int* order   = (int*)(WT1 + (size_t)ND * HH * 128);
    int* inv     = order + MAXS;
    int* deg     = inv + TOTAL;
    int* cnt     = deg + TOTAL;
    int* base_bd = cnt + BB * 8;
    int* tdeg    = base_bd + BB * 8;

    hipLaunchKernelGGL(k_hist_bd, dim3(BB), dim3(NN), 0, stream, e, deg, cnt);
    hipLaunchKernelGGL(k_scan_bd, dim3(1), dim3(256), 0, stream, cnt, base_bd, tdeg);
    hipLaunchKernelGGL(k_init_order, dim3(MAXS / 512), dim3(512), 0, stream, order);
    hipLaunchKernelGGL(k_scatter, dim3(BB), dim3(NN), 0, stream, deg, base_bd, order, inv);
    hipLaunchKernelGGL(k_prep_wt, dim3(HH, ND), dim3(64), 0, stream, W0, WT0, F_IN, 64);
    hipLaunchKernelGGL(k_prep_wt, dim3(HH, ND), dim3(64), 0, stream, W1, WT1, HH, HH);

    const int lds1 = 128 * 64 * 2 + 128 * STG * 2;    // 50176
    const int lds2 = 128 * 128 * 2 + 128 * STG * 2;   // 66560
    (void)hipFuncSetAttribute((const void*)k_gemm_big<8>,
                              hipFuncAttributeMaxDynamicSharedMemorySize, lds1);
    (void)hipFuncSetAttribute((const void*)k_gemm_big<16>,
                              hipFuncAttributeMaxDynamicSharedMemorySize, lds2);

    hipLaunchKernelGGL(k_gather1, dim3(MAXS * 8 / 512), dim3(512), 0, stream,
                       a, e, order, bufB);
    hipLaunchKernelGGL((k_gemm_big<8>), dim3(MAXT), dim3(512), lds1, stream,
                       bufB, WT0, b0, tdeg, bufA);
    hipLaunchKernelGGL(k_pool_bf, dim3(TOTAL / 16), dim3(256), 0, stream, bufA, e, inv, bufB);
    hipLaunchKernelGGL(k_gather2, dim3(MAXS * 16 / 512), dim3(512), 0, stream,
                       bufB, e, order, bufA);
    hipLaunchKernelGGL((k_gemm_big<16>), dim3(MAXT), dim3(512), lds2, stream,
                       bufA, WT1, b1, tdeg, bufB);
    hipLaunchKernelGGL(k_pool_sum_part, dim3(BB * 32), dim3(256), 0, stream, bufB, e, inv, partial);
    hipLaunchKernelGGL(k_sum_final, dim3(BB * HH / 256), dim3(256), 0, stream, partial, out);
}

// Round 12
// 187.534 us; speedup vs baseline: 1.2461x; 1.2461x over previous
//
#include <hip/hip_runtime.h>
#include <math.h>

#define BB 256
#define NN 512
#define DD 6
#define F_IN 62
#define HH 128
#define ND 7
#define TOTAL (BB*NN)     // 131072
#define MAXS 132096       // padded slots: 1032 tiles x 128
#define MAXT 1032         // 128-row degree-pure tiles
#define STG 132           // epilogue staging row stride (bank-spread)

typedef __bf16 bf16x8 __attribute__((ext_vector_type(8)));
typedef float f32x4 __attribute__((ext_vector_type(4)));

__device__ __forceinline__ unsigned short f2bf(float f) {
    unsigned u = __builtin_bit_cast(unsigned, f);
    u = (u + 0x7FFFu + ((u >> 16) & 1u)) >> 16;
    return (unsigned short)u;
}
__device__ __forceinline__ float lo2f(unsigned x) { return __builtin_bit_cast(float, x << 16); }
__device__ __forceinline__ float hi2f(unsigned x) { return __builtin_bit_cast(float, x & 0xFFFF0000u); }

__device__ __forceinline__ uint4 pack8(const float* s) {
    uint4 r;
    r.x = (unsigned)f2bf(s[0]) | ((unsigned)f2bf(s[1]) << 16);
    r.y = (unsigned)f2bf(s[2]) | ((unsigned)f2bf(s[3]) << 16);
    r.z = (unsigned)f2bf(s[4]) | ((unsigned)f2bf(s[5]) << 16);
    r.w = (unsigned)f2bf(s[6]) | ((unsigned)f2bf(s[7]) << 16);
    return r;
}
__device__ __forceinline__ void unpack_add(float* s, uint4 q) {
    s[0] += lo2f(q.x); s[1] += hi2f(q.x); s[2] += lo2f(q.y); s[3] += hi2f(q.y);
    s[4] += lo2f(q.z); s[5] += hi2f(q.z); s[6] += lo2f(q.w); s[7] += hi2f(q.w);
}
__device__ __forceinline__ void unpack_max(float* s, uint4 q) {
    s[0] = fmaxf(s[0], lo2f(q.x)); s[1] = fmaxf(s[1], hi2f(q.x));
    s[2] = fmaxf(s[2], lo2f(q.y)); s[3] = fmaxf(s[3], hi2f(q.y));
    s[4] = fmaxf(s[4], lo2f(q.z)); s[5] = fmaxf(s[5], hi2f(q.z));
    s[6] = fmaxf(s[6], lo2f(q.w)); s[7] = fmaxf(s[7], hi2f(q.w));
}
__device__ __forceinline__ void rowadd62(float* s, const float* r, int kb) {
    float2 z0 = *(const float2*)(r);     s[0] += z0.x; s[1] += z0.y;
    float2 z1 = *(const float2*)(r + 2); s[2] += z1.x; s[3] += z1.y;
    float2 z2 = *(const float2*)(r + 4); s[4] += z2.x; s[5] += z2.y;
    if (kb < 7) { float2 z3 = *(const float2*)(r + 6); s[6] += z3.x; s[7] += z3.y; }
}

// ---------------- global stable degree sort, buckets padded to 128 ----------------

__global__ __launch_bounds__(512) void k_hist_bd(const int* __restrict__ e,
                                                 int* __restrict__ deg,
                                                 int* __restrict__ cnt) {
    __shared__ unsigned int lh[ND];
    const int b = blockIdx.x;
    const int t = threadIdx.x;
    if (t < ND) lh[t] = 0u;
    __syncthreads();
    int d = 0;
#pragma unroll
    for (int j = 0; j < DD; ++j) d += (e[(b * NN + t) * DD + j] >= 0) ? 1 : 0;
    deg[b * NN + t] = d;
    atomicAdd(&lh[d], 1u);
    __syncthreads();
    if (t < ND) cnt[b * 8 + t] = (int)lh[t];
}

// parallel scan: LDS-staged, per-degree threads scan batches (was 41 us serial, now ~4)
__global__ __launch_bounds__(256) void k_scan_bd(const int* __restrict__ cnt,
                                                 int* __restrict__ base_bd,
                                                 int* __restrict__ tdeg) {
    __shared__ int lc[BB * 8];
    __shared__ int gb[8];
    const int t = threadIdx.x;
    for (int i = t; i < BB * 8; i += 256) lc[i] = cnt[i];
    __syncthreads();
    if (t < ND) {
        int s = 0;
#pragma unroll 8
        for (int b = 0; b < BB; ++b) s += lc[b * 8 + t];
        gb[t] = s;
    }
    __syncthreads();
    if (t == 0) {
        int acc = 0;
        for (int d = 0; d < ND; ++d) { int tot = gb[d]; gb[d] = acc; acc += (tot + 127) & ~127; }
        gb[7] = acc;
    }
    __syncthreads();
    if (t < ND) {
        int r = gb[t];
        for (int b = 0; b < BB; ++b) { base_bd[b * 8 + t] = r; r += lc[b * 8 + t]; }
    }
    __syncthreads();
    for (int i = t; i < MAXT; i += 256) {
        int s = i * 128;
        int dd = 0;
        for (int d = ND - 1; d >= 0; --d) if (s >= gb[d]) { dd = d; break; }
        tdeg[i] = (s < gb[7]) ? dd : 0;
    }
}

__global__ __launch_bounds__(512) void k_init_order(int* __restrict__ order) {
    order[blockIdx.x * 512 + threadIdx.x] = -1;
}

__global__ __launch_bounds__(512) void k_scatter(const int* __restrict__ deg,
                                                 const int* __restrict__ base_bd,
                                                 int* __restrict__ order) {
    __shared__ unsigned int rk[ND];
    const int b = blockIdx.x;
    const int t = threadIdx.x;
    if (t < ND) rk[t] = 0u;
    __syncthreads();
    const int u = b * NN + t;
    const int d = deg[u];
    unsigned r = atomicAdd(&rk[d], 1u);
    order[base_bd[b * 8 + d] + (int)r] = u;
}

// ---------------- prep: W [ND][F][HH] f32 -> WT [ND][HH][K] bf16 (K-contig, pad) ----------------

__global__ void k_prep_wt(const float* __restrict__ W, unsigned short* __restrict__ WT,
                          int F, int K) {
    int n = blockIdx.x;
    int d = blockIdx.y;
    for (int k = threadIdx.x; k < K; k += 64) {
        float v = (k < F) ? W[((size_t)d * F + k) * HH + n] : 0.f;
        WT[((size_t)d * HH + n) * K + k] = f2bf(v);
    }
}

// ---------------- gather1: S1[slot][0..64) = a[v] + sum(a[nbr]) (sorted layout) ----------------

__global__ __launch_bounds__(512)
void k_gather1(const float* __restrict__ a, const int* __restrict__ e,
               const int* __restrict__ order, unsigned short* __restrict__ S1) {
    const int u = blockIdx.x * 512 + threadIdx.x;
    const int slot = u >> 3;
    const int kb = u & 7;
    const int v = order[slot];
    if (v < 0) return;
    const int* ep = e + (size_t)v * DD;
    const int nb = v & ~(NN - 1);
    float s[8] = {0.f, 0.f, 0.f, 0.f, 0.f, 0.f, 0.f, 0.f};
    rowadd62(s, a + (size_t)v * F_IN + kb * 8, kb);
#pragma unroll
    for (int jj = 0; jj < DD; ++jj) {
        int idx = ep[jj];
        if (idx >= 0) rowadd62(s, a + (size_t)(nb + idx) * F_IN + kb * 8, kb);
    }
    *(uint4*)(S1 + (size_t)slot * 64 + kb * 8) = pack8(s);
}

// ---------------- gather2: S2[slot][0..128) = p1[v] + sum(p1[nbr]) (natural -> sorted) ---------

__global__ __launch_bounds__(512)
void k_gather2(const unsigned short* __restrict__ P1, const int* __restrict__ e,
               const int* __restrict__ order, unsigned short* __restrict__ S2) {
    const int u = blockIdx.x * 512 + threadIdx.x;
    const int slot = u >> 4;
    const int kb = u & 15;
    const int v = order[slot];
    if (v < 0) return;
    const int* ep = e + (size_t)v * DD;
    const int nb = v & ~(NN - 1);
    const unsigned short* base = P1 + kb * 8;
    float s[8] = {0.f, 0.f, 0.f, 0.f, 0.f, 0.f, 0.f, 0.f};
    unpack_add(s, *(const uint4*)(base + (size_t)v * HH));
#pragma unroll
    for (int jj = 0; jj < DD; ++jj) {
        int idx = ep[jj];
        if (idx >= 0) unpack_add(s, *(const uint4*)(base + (size_t)(nb + idx) * HH));
    }
    *(uint4*)(S2 + (size_t)slot * HH + kb * 8) = pack8(s);
}

// ---------------- degree-pure 128-row tile GEMM, W[d] in LDS, NATURAL-layout scatter store -----
// Block = 1 tile (128 sorted rows), 8 waves; wave w = rows [w*16, w*16+16).
// A-frags straight from sorted S (global, issued before W barrier). B from LDS W[d] (once/block).
// Epilogue scatters rows to natural node layout (1-3 batch windows per tile - L2-local).

template<int KB>   // 8 (K=64) or 16 (K=128)
__global__ __launch_bounds__(512, 4)
void k_gemm_big(const unsigned short* __restrict__ S,
                const unsigned short* __restrict__ WT, const float* __restrict__ bias,
                const int* __restrict__ tdeg, const int* __restrict__ order,
                unsigned short* __restrict__ Y) {
    constexpr int K = KB * 8;
    constexpr int KK = KB / 4;
    constexpr int LOGKB = (KB == 16) ? 4 : 3;
    extern __shared__ char smem[];
    unsigned short* Wl  = (unsigned short*)smem;                  // 128 x K, swizzled
    unsigned short* stg = (unsigned short*)(smem + 128 * K * 2);  // 128 x STG
    __shared__ int vT[128];

    const int t = threadIdx.x;
    const int l = t & 63;
    const int w = t >> 6;
    const int lr = l & 15;
    const int lq = l >> 4;

    const int tile = blockIdx.x;
    const int d = tdeg[tile];

    if (t < 128) vT[t] = order[tile * 128 + t];

    // stage W[d] -> LDS (coalesced, XOR-swizzled rows)
    for (int u = t; u < 128 * KB; u += 512) {
        const int row = u >> LOGKB;
        const int kb = u & (KB - 1);
        *(uint4*)&Wl[(row * KB + (kb ^ (row & 7))) * 8] =
            *(const uint4*)(WT + ((size_t)d * HH + row) * K + kb * 8);
    }

    // A fragments straight from global sorted S (independent of W staging)
    const unsigned short* sp = S + (size_t)(tile * 128 + w * 16 + lr) * K;
    bf16x8 af[KK];
#pragma unroll
    for (int kk = 0; kk < KK; ++kk)
        af[kk] = *(const bf16x8*)(sp + (lq + 4 * kk) * 8);

    __syncthreads();   // W + vT ready

#pragma unroll
    for (int fr = 0; fr < 8; ++fr) {
        const int col = fr * 16 + lr;
        f32x4 z = {0.f, 0.f, 0.f, 0.f};
#pragma unroll
        for (int kk = 0; kk < KK; ++kk) {
            bf16x8 bfr = *(const bf16x8*)&Wl[(col * KB + ((kk * 4 + lq) ^ (col & 7))) * 8];
            z = __builtin_amdgcn_mfma_f32_16x16x32_bf16(af[kk], bfr, z, 0, 0, 0);
        }
        const float bv = bias[d * HH + col];
#pragma unroll
        for (int r2 = 0; r2 < 4; ++r2) {
            float zz = 1.f / (1.f + __expf(-(z[r2] + bv)));
            stg[(w * 16 + lq * 4 + r2) * STG + col] = f2bf(zz);
        }
    }

    __syncthreads();
    for (int u = t; u < 2048; u += 512) {
        const int n = u >> 4;
        const int c8 = (u & 15) * 8;
        const int v = vT[n];
        if (v >= 0) {
            uint4 p = *(const uint4*)&stg[n * STG + c8];
            *(uint4*)&Y[(size_t)v * HH + c8] = p;
        }
    }
}

// ---------------- pool1: natural in/out, batch-local gathers ----------------

__global__ __launch_bounds__(256) void k_pool_bf(const unsigned short* __restrict__ X,
                                                 const int* __restrict__ e,
                                                 unsigned short* __restrict__ P) {
    const int t = threadIdx.x;
    const int u = blockIdx.x * 16 + (t >> 4);
    const int c8 = (t & 15) * 8;
    const int nb = u & ~(NN - 1);
    float m[8];
    {
        uint4 p = *(const uint4*)(X + (size_t)u * HH + c8);
        m[0] = lo2f(p.x); m[1] = hi2f(p.x); m[2] = lo2f(p.y); m[3] = hi2f(p.y);
        m[4] = lo2f(p.z); m[5] = hi2f(p.z); m[6] = lo2f(p.w); m[7] = hi2f(p.w);
    }
#pragma unroll
    for (int jj = 0; jj < DD; ++jj) {
        int idx = e[u * DD + jj];
        if (idx >= 0) unpack_max(m, *(const uint4*)(X + (size_t)(nb + idx) * HH + c8));
    }
    *(uint4*)&P[(size_t)u * HH + c8] = pack8(m);
}

// ---------------- final: pool (natural) + partial sum (32 blocks/batch) ------------------------

__global__ __launch_bounds__(256) void k_pool_sum_part(const unsigned short* __restrict__ X,
                                                       const int* __restrict__ e,
                                                       float* __restrict__ partial) {
    __shared__ float red[16][HH + 4];
    const int t = threadIdx.x;
    const int b = blockIdx.x >> 5;
    const int chunk = blockIdx.x & 31;
    const int slot = t >> 4;
    const int c8 = (t & 15) * 8;

    const int u = b * NN + chunk * 16 + slot;
    float m[8];
    {
        uint4 p = *(const uint4*)(X + (size_t)u * HH + c8);
        m[0] = lo2f(p.x); m[1] = hi2f(p.x); m[2] = lo2f(p.y); m[3] = hi2f(p.y);
        m[4] = lo2f(p.z); m[5] = hi2f(p.z); m[6] = lo2f(p.w); m[7] = hi2f(p.w);
    }
#pragma unroll
    for (int jj = 0; jj < DD; ++jj) {
        int idx = e[u * DD + jj];
        if (idx >= 0) unpack_max(m, *(const uint4*)(X + (size_t)(b * NN + idx) * HH + c8));
    }
#pragma unroll
    for (int i = 0; i < 8; ++i) red[slot][c8 + i] = m[i];
    __syncthreads();
    if (t < HH) {
        float s = 0.f;
#pragma unroll
        for (int k = 0; k < 16; ++k) s += red[k][t];
        partial[((size_t)b * 32 + chunk) * HH + t] = s;
    }
}

__global__ __launch_bounds__(256) void k_sum_final(const float* __restrict__ partial,
                                                   float* __restrict__ out) {
    int g = blockIdx.x * 256 + threadIdx.x;
    int b = g >> 7;
    int c = g & 127;
    float s = 0.f;
#pragma unroll
    for (int k = 0; k < 32; ++k) s += partial[((size_t)b * 32 + k) * HH + c];
    out[g] = s;
}

// ---------------- launcher ----------------
// ws regions (lifetimes disjoint):
//   A [0, 33.8M):      S1 (gather1->gemm1) -> S2 (gather2->gemm2)
//   B [33.8M, 67.4M):  h1 natural (gemm1->pool1) -> h2 natural (gemm2->pool_sum)
//   C [67.4M, 100.9M): p1 natural (pool1->gather2) -> partial (4 MB)
//   meta [100.9M+):    WT0, WT1, order, deg, cnt, base_bd, tdeg  (~102.4 MB total)

extern "C" void kernel_launch(void* const* d_in, const int* in_sizes, int n_in,
                              void* d_out, int out_size, void* d_ws, size_t ws_size,
                              hipStream_t stream) {
    const float* a  = (const float*)d_in[0];
    const int*   e  = (const int*)d_in[1];
    const float* W0 = (const float*)d_in[2];
    const float* b0 = (const float*)d_in[3];
    const float* W1 = (const float*)d_in[4];
    const float* b1 = (const float*)d_in[5];
    float* out = (float*)d_out;

    char* ws = (char*)d_ws;
    const size_t SA = (size_t)MAXS * HH * 2;    // 33,816,576
    const size_t SB = (size_t)TOTAL * HH * 2;   // 33,554,432
    unsigned short* bufS = (unsigned short*)ws;             // S1 / S2
    unsigned short* bufH = (unsigned short*)(ws + SA);      // h1 / h2 (natural)
    unsigned short* bufP = (unsigned short*)(ws + SA + SB); // p1 (natural)
    float* partial = (float*)bufP;
    char* dp = ws + SA + 2 * SB;
    unsigned short* WT0 = (unsigned short*)dp;
    unsigned short* WT1 = WT0 + (size_t)ND * HH * 64;
    int* order   = (int*)(WT1 + (size_t)ND * HH * 128);
    int* deg     = order + MAXS;
    int* cnt     = deg + TOTAL;
    int* base_bd = cnt + BB * 8;
    int* tdeg    = base_bd + BB * 8;

    hipLaunchKernelGGL(k_hist_bd, dim3(BB), dim3(NN), 0, stream, e, deg, cnt);
    hipLaunchKernelGGL(k_scan_bd, dim3(1), dim3(256), 0, stream, cnt, base_bd, tdeg);
    hipLaunchKernelGGL(k_init_order, dim3(MAXS / 512), dim3(512), 0, stream, order);
    hipLaunchKernelGGL(k_scatter, dim3(BB), dim3(NN), 0, stream, deg, base_bd, order);
    hipLaunchKernelGGL(k_prep_wt, dim3(HH, ND), dim3(64), 0, stream, W0, WT0, F_IN, 64);
    hipLaunchKernelGGL(k_prep_wt, dim3(HH, ND), dim3(64), 0, stream, W1, WT1, HH, HH);

    const int lds1 = 128 * 64 * 2 + 128 * STG * 2;    // 50176
    const int lds2 = 128 * 128 * 2 + 128 * STG * 2;   // 66560
    (void)hipFuncSetAttribute((const void*)k_gemm_big<8>,
                              hipFuncAttributeMaxDynamicSharedMemorySize, lds1);
    (void)hipFuncSetAttribute((const void*)k_gemm_big<16>,
                              hipFuncAttributeMaxDynamicSharedMemorySize, lds2);

    hipLaunchKernelGGL(k_gather1, dim3(MAXS * 8 / 512), dim3(512), 0, stream,
                       a, e, order, bufS);
    hipLaunchKernelGGL((k_gemm_big<8>), dim3(MAXT), dim3(512), lds1, stream,
                       bufS, WT0, b0, tdeg, order, bufH);
    hipLaunchKernelGGL(k_pool_bf, dim3(TOTAL / 16), dim3(256), 0, stream, bufH, e, bufP);
    hipLaunchKernelGGL(k_gather2, dim3(MAXS * 16 / 512), dim3(512), 0, stream,
                       bufP, e, order, bufS);
    hipLaunchKernelGGL((k_gemm_big<16>), dim3(MAXT), dim3(512), lds2, stream,
                       bufS, WT1, b1, tdeg, order, bufH);
    hipLaunchKernelGGL(k_pool_sum_part, dim3(BB * 32), dim3(256), 0, stream, bufH, e, partial);
    hipLaunchKernelGGL(k_sum_final, dim3(BB * HH / 256), dim3(256), 0, stream, partial, out);
}

// Round 13
// 165.064 us; speedup vs baseline: 1.4158x; 1.1361x over previous
//
#include <hip/hip_runtime.h>
#include <math.h>

#define BB 256
#define NN 512
#define DD 6
#define F_IN 62
#define HH 128
#define ND 7
#define TOTAL (BB*NN)      // 131072
#define G8 8               // batches per sort group
#define NG 32              // groups
#define GOPB 5120          // slots per group (4096 + bucket padding headroom, mult of 128)
#define MAXSG (NG*GOPB)    // 163840
#define T128 (MAXSG/128)   // 1280 conv1 tiles
#define T64  (MAXSG/64)    // 2560 conv2 tiles
#define STG 132            // epilogue staging row stride

typedef __bf16 bf16x8 __attribute__((ext_vector_type(8)));
typedef float f32x4 __attribute__((ext_vector_type(4)));

__device__ __forceinline__ unsigned short f2bf(float f) {
    unsigned u = __builtin_bit_cast(unsigned, f);
    u = (u + 0x7FFFu + ((u >> 16) & 1u)) >> 16;
    return (unsigned short)u;
}
__device__ __forceinline__ float lo2f(unsigned x) { return __builtin_bit_cast(float, x << 16); }
__device__ __forceinline__ float hi2f(unsigned x) { return __builtin_bit_cast(float, x & 0xFFFF0000u); }

__device__ __forceinline__ uint4 pack8(const float* s) {
    uint4 r;
    r.x = (unsigned)f2bf(s[0]) | ((unsigned)f2bf(s[1]) << 16);
    r.y = (unsigned)f2bf(s[2]) | ((unsigned)f2bf(s[3]) << 16);
    r.z = (unsigned)f2bf(s[4]) | ((unsigned)f2bf(s[5]) << 16);
    r.w = (unsigned)f2bf(s[6]) | ((unsigned)f2bf(s[7]) << 16);
    return r;
}
__device__ __forceinline__ void unpack_add(float* s, uint4 q) {
    s[0] += lo2f(q.x); s[1] += hi2f(q.x); s[2] += lo2f(q.y); s[3] += hi2f(q.y);
    s[4] += lo2f(q.z); s[5] += hi2f(q.z); s[6] += lo2f(q.w); s[7] += hi2f(q.w);
}
__device__ __forceinline__ void unpack_max(float* s, uint4 q) {
    s[0] = fmaxf(s[0], lo2f(q.x)); s[1] = fmaxf(s[1], hi2f(q.x));
    s[2] = fmaxf(s[2], lo2f(q.y)); s[3] = fmaxf(s[3], hi2f(q.y));
    s[4] = fmaxf(s[4], lo2f(q.z)); s[5] = fmaxf(s[5], hi2f(q.z));
    s[6] = fmaxf(s[6], lo2f(q.w)); s[7] = fmaxf(s[7], hi2f(q.w));
}
__device__ __forceinline__ void rowadd62(float* s, const float* r, int kb) {
    float2 z0 = *(const float2*)(r);     s[0] += z0.x; s[1] += z0.y;
    float2 z1 = *(const float2*)(r + 2); s[2] += z1.x; s[3] += z1.y;
    float2 z2 = *(const float2*)(r + 4); s[4] += z2.x; s[5] += z2.y;
    if (kb < 7) { float2 z3 = *(const float2*)(r + 6); s[6] += z3.x; s[7] += z3.y; }
}

// ---------------- per-batch degree histogram ----------------

__global__ __launch_bounds__(512) void k_hist(const int* __restrict__ e,
                                              int* __restrict__ deg,
                                              int* __restrict__ cnt) {
    __shared__ unsigned int lh[ND];
    const int b = blockIdx.x;
    const int t = threadIdx.x;
    if (t < ND) lh[t] = 0u;
    __syncthreads();
    int d = 0;
#pragma unroll
    for (int j = 0; j < DD; ++j) d += (e[(b * NN + t) * DD + j] >= 0) ? 1 : 0;
    deg[b * NN + t] = d;
    atomicAdd(&lh[d], 1u);
    __syncthreads();
    if (t < ND) cnt[b * 8 + t] = (int)lh[t];
}

// ---------------- group-local scan: buckets padded to 128 within each 8-batch group ------------

__global__ __launch_bounds__(256) void k_scan_grp(const int* __restrict__ cnt,
                                                  int* __restrict__ base_bd,
                                                  int* __restrict__ tdeg64) {
    __shared__ int lc[BB * 8];
    __shared__ int bnd[NG][8];
    const int t = threadIdx.x;
    for (int i = t; i < BB * 8; i += 256) lc[i] = cnt[i];
    __syncthreads();
    if (t < NG) {
        int acc = t * GOPB;
        for (int d = 0; d < ND; ++d) {
            bnd[t][d] = acc;
            for (int b8 = 0; b8 < G8; ++b8) {
                int b = t * G8 + b8;
                base_bd[b * 8 + d] = acc;
                acc += lc[b * 8 + d];
            }
            acc = (acc + 127) & ~127;
        }
        bnd[t][7] = acc;
    }
    __syncthreads();
    for (int i = t; i < T64; i += 256) {
        int g = i / (GOPB / 64);
        int s = i * 64;
        int dd = 0;
        if (s < bnd[g][7]) {
            for (int d = ND - 1; d >= 0; --d) if (s >= bnd[g][d]) { dd = d; break; }
        }
        tdeg64[i] = dd;
    }
}

__global__ __launch_bounds__(512) void k_init_order(int* __restrict__ order) {
    order[blockIdx.x * 512 + threadIdx.x] = -1;
}

__global__ __launch_bounds__(512) void k_scatter(const int* __restrict__ deg,
                                                 const int* __restrict__ base_bd,
                                                 int* __restrict__ order) {
    __shared__ unsigned int rk[ND];
    const int b = blockIdx.x;
    const int t = threadIdx.x;
    if (t < ND) rk[t] = 0u;
    __syncthreads();
    const int u = b * NN + t;
    const int d = deg[u];
    unsigned r = atomicAdd(&rk[d], 1u);
    order[base_bd[b * 8 + d] + (int)r] = u;
}

// ---------------- prep: W [ND][F][HH] f32 -> WT [ND][HH][K] bf16 (K-contig, pad) ----------------

__global__ void k_prep_wt(const float* __restrict__ W, unsigned short* __restrict__ WT,
                          int F, int K) {
    int n = blockIdx.x;
    int d = blockIdx.y;
    for (int k = threadIdx.x; k < K; k += 64) {
        float v = (k < F) ? W[((size_t)d * F + k) * HH + n] : 0.f;
        WT[((size_t)d * HH + n) * K + k] = f2bf(v);
    }
}

// ---------------- conv1: fused gather(a) + MFMA, 128-row degree-pure tile, W in LDS ------------
// Grid 1280 = 8 XCD x 160; group g's tiles all on XCD g/4. 512 threads, ~50 KB LDS -> 3 blk/CU.

__global__ __launch_bounds__(512, 6)
void k_conv1(const float* __restrict__ a, const int* __restrict__ e,
             const unsigned short* __restrict__ WT, const float* __restrict__ bias,
             const int* __restrict__ order, const int* __restrict__ tdeg64,
             unsigned short* __restrict__ Y) {
    extern __shared__ char smem[];
    unsigned short* Wl = (unsigned short*)smem;            // 16 KB swizzled W[d]
    unsigned short* sA = (unsigned short*)(smem + 16384);  // 16 KB A tile; stg alias (33792 B)
    unsigned short* stg = sA;
    __shared__ int vT[128];

    const int t = threadIdx.x;
    const int l = t & 63;
    const int w = t >> 6;
    const int lr = l & 15;
    const int lq = l >> 4;

    const int x8 = blockIdx.x & 7;
    const int kk0 = blockIdx.x >> 3;              // 0..159
    const int g = x8 * 4 + kk0 / 40;
    const int tile = g * 40 + (kk0 % 40);

    if (order[tile * 128] < 0) return;            // fully-pad tile
    const int d = tdeg64[tile * 2];

    if (t < 128) vT[t] = order[tile * 128 + t];
    for (int u = t; u < 1024; u += 512) {         // W[d]: 128 cols x 8 kb
        const int col = u >> 3, kb = u & 7;
        *(uint4*)&Wl[(col * 8 + (kb ^ (col & 7))) * 8] =
            *(const uint4*)(WT + ((size_t)d * HH + col) * 64 + kb * 8);
    }
    __syncthreads();                              // vT + Wl ready

    for (int u = t; u < 1024; u += 512) {         // gather: n 0..127, kb 0..7
        const int n = u >> 3, kb = u & 7;
        const int v = vT[n];
        float s[8] = {0.f, 0.f, 0.f, 0.f, 0.f, 0.f, 0.f, 0.f};
        if (v >= 0) {
            const int nb = v & ~(NN - 1);
            const int* ep = e + (size_t)v * DD;
            rowadd62(s, a + (size_t)v * F_IN + kb * 8, kb);
#pragma unroll
            for (int jj = 0; jj < DD; ++jj) {
                int idx = ep[jj];
                if (idx >= 0) rowadd62(s, a + (size_t)(nb + idx) * F_IN + kb * 8, kb);
            }
        }
        *(uint4*)&sA[(n * 8 + (kb ^ (n & 7))) * 8] = pack8(s);
    }
    __syncthreads();                              // sA ready

    const int nrow = w * 16 + lr;
    bf16x8 af[2];
    af[0] = *(const bf16x8*)&sA[(nrow * 8 + ((0 + lq) ^ (nrow & 7))) * 8];
    af[1] = *(const bf16x8*)&sA[(nrow * 8 + ((4 + lq) ^ (nrow & 7))) * 8];

    f32x4 acc[8];
#pragma unroll
    for (int fr = 0; fr < 8; ++fr) {
        const int col = fr * 16 + lr;
        f32x4 z = {0.f, 0.f, 0.f, 0.f};
#pragma unroll
        for (int kk = 0; kk < 2; ++kk) {
            bf16x8 bfr = *(const bf16x8*)&Wl[(col * 8 + ((4 * kk + lq) ^ (col & 7))) * 8];
            z = __builtin_amdgcn_mfma_f32_16x16x32_bf16(af[kk], bfr, z, 0, 0, 0);
        }
        acc[fr] = z;
    }

    __syncthreads();                              // all sA reads done; stg aliases sA
#pragma unroll
    for (int fr = 0; fr < 8; ++fr) {
        const int col = fr * 16 + lr;
        const float bv = bias[d * HH + col];
#pragma unroll
        for (int r2 = 0; r2 < 4; ++r2) {
            float zz = 1.f / (1.f + __expf(-(acc[fr][r2] + bv)));
            stg[(w * 16 + lq * 4 + r2) * STG + col] = f2bf(zz);
        }
    }
    __syncthreads();
    for (int u = t; u < 2048; u += 512) {         // scatter-store natural (group-local)
        const int n = u >> 4, c8 = (u & 15) * 8;
        const int v = vT[n];
        if (v >= 0)
            *(uint4*)&Y[(size_t)v * HH + c8] = *(const uint4*)&stg[n * STG + c8];
    }
}

// ---------------- conv2: fused gather(p1) + MFMA, 64-row degree-pure tile, W in LDS ------------
// Grid 2560 = 8 XCD x 320. 512 threads (8 waves: 4 row-groups x 2 col-halves), ~49 KB -> 3 blk/CU.

__global__ __launch_bounds__(512, 6)
void k_conv2(const unsigned short* __restrict__ P1, const int* __restrict__ e,
             const unsigned short* __restrict__ WT, const float* __restrict__ bias,
             const int* __restrict__ order, const int* __restrict__ tdeg64,
             unsigned short* __restrict__ Y) {
    extern __shared__ char smem[];
    unsigned short* Wl = (unsigned short*)smem;            // 32 KB swizzled W[d]
    unsigned short* sA = (unsigned short*)(smem + 32768);  // 16 KB A tile; stg alias (16896 B)
    unsigned short* stg = sA;
    __shared__ int vT[64];

    const int t = threadIdx.x;
    const int l = t & 63;
    const int w = t >> 6;
    const int lr = l & 15;
    const int lq = l >> 4;

    const int x8 = blockIdx.x & 7;
    const int kk0 = blockIdx.x >> 3;              // 0..319
    const int g = x8 * 4 + kk0 / 80;
    const int tile = g * 80 + (kk0 % 80);

    if (order[tile * 64] < 0) return;
    const int d = tdeg64[tile];

    if (t < 64) vT[t] = order[tile * 64 + t];
    for (int u = t; u < 2048; u += 512) {         // W[d]: 128 cols x 16 kb
        const int col = u >> 4, kb = u & 15;
        *(uint4*)&Wl[(col * 16 + (kb ^ (col & 7))) * 8] =
            *(const uint4*)(WT + ((size_t)d * HH + col) * 128 + kb * 8);
    }
    __syncthreads();                              // vT + Wl ready

    for (int u = t; u < 1024; u += 512) {         // gather: n 0..63, kb 0..15
        const int n = u >> 4, kb = u & 15;
        const int v = vT[n];
        float s[8] = {0.f, 0.f, 0.f, 0.f, 0.f, 0.f, 0.f, 0.f};
        if (v >= 0) {
            const int nb = v & ~(NN - 1);
            const int* ep = e + (size_t)v * DD;
            const unsigned short* base = P1 + kb * 8;
            unpack_add(s, *(const uint4*)(base + (size_t)v * HH));
#pragma unroll
            for (int jj = 0; jj < DD; ++jj) {
                int idx = ep[jj];
                if (idx >= 0) unpack_add(s, *(const uint4*)(base + (size_t)(nb + idx) * HH));
            }
        }
        *(uint4*)&sA[(n * 16 + (kb ^ (n & 7))) * 8] = pack8(s);
    }
    __syncthreads();                              // sA ready

    const int nrow = (w & 3) * 16 + lr;
    const int ch = w >> 2;
    bf16x8 af[4];
#pragma unroll
    for (int kk = 0; kk < 4; ++kk)
        af[kk] = *(const bf16x8*)&sA[(nrow * 16 + ((4 * kk + lq) ^ (nrow & 7))) * 8];

    f32x4 acc[4];
#pragma unroll
    for (int fr = 0; fr < 4; ++fr) {
        const int col = ch * 64 + fr * 16 + lr;
        f32x4 z = {0.f, 0.f, 0.f, 0.f};
#pragma unroll
        for (int kk = 0; kk < 4; ++kk) {
            bf16x8 bfr = *(const bf16x8*)&Wl[(col * 16 + ((4 * kk + lq) ^ (col & 7))) * 8];
            z = __builtin_amdgcn_mfma_f32_16x16x32_bf16(af[kk], bfr, z, 0, 0, 0);
        }
        acc[fr] = z;
    }

    __syncthreads();                              // all sA reads done; stg aliases sA
#pragma unroll
    for (int fr = 0; fr < 4; ++fr) {
        const int col = ch * 64 + fr * 16 + lr;
        const float bv = bias[d * HH + col];
#pragma unroll
        for (int r2 = 0; r2 < 4; ++r2) {
            float zz = 1.f / (1.f + __expf(-(acc[fr][r2] + bv)));
            stg[((w & 3) * 16 + lq * 4 + r2) * STG + col] = f2bf(zz);
        }
    }
    __syncthreads();
    for (int u = t; u < 1024; u += 512) {
        const int n = u >> 4, c8 = (u & 15) * 8;
        const int v = vT[n];
        if (v >= 0)
            *(uint4*)&Y[(size_t)v * HH + c8] = *(const uint4*)&stg[n * STG + c8];
    }
}

// ---------------- pool1: natural in/out, batch-local ----------------

__global__ __launch_bounds__(256) void k_pool_bf(const unsigned short* __restrict__ X,
                                                 const int* __restrict__ e,
                                                 unsigned short* __restrict__ P) {
    const int t = threadIdx.x;
    const int u = blockIdx.x * 16 + (t >> 4);
    const int c8 = (t & 15) * 8;
    const int nb = u & ~(NN - 1);
    float m[8];
    {
        uint4 p = *(const uint4*)(X + (size_t)u * HH + c8);
        m[0] = lo2f(p.x); m[1] = hi2f(p.x); m[2] = lo2f(p.y); m[3] = hi2f(p.y);
        m[4] = lo2f(p.z); m[5] = hi2f(p.z); m[6] = lo2f(p.w); m[7] = hi2f(p.w);
    }
#pragma unroll
    for (int jj = 0; jj < DD; ++jj) {
        int idx = e[u * DD + jj];
        if (idx >= 0) unpack_max(m, *(const uint4*)(X + (size_t)(nb + idx) * HH + c8));
    }
    *(uint4*)&P[(size_t)u * HH + c8] = pack8(m);
}

// ---------------- final: pool (natural) + partial sum (32 blocks/batch) ------------------------

__global__ __launch_bounds__(256) void k_pool_sum_part(const unsigned short* __restrict__ X,
                                                       const int* __restrict__ e,
                                                       float* __restrict__ partial) {
    __shared__ float red[16][HH + 4];
    const int t = threadIdx.x;
    const int b = blockIdx.x >> 5;
    const int chunk = blockIdx.x & 31;
    const int slot = t >> 4;
    const int c8 = (t & 15) * 8;

    const int u = b * NN + chunk * 16 + slot;
    float m[8];
    {
        uint4 p = *(const uint4*)(X + (size_t)u * HH + c8);
        m[0] = lo2f(p.x); m[1] = hi2f(p.x); m[2] = lo2f(p.y); m[3] = hi2f(p.y);
        m[4] = lo2f(p.z); m[5] = hi2f(p.z); m[6] = lo2f(p.w); m[7] = hi2f(p.w);
    }
#pragma unroll
    for (int jj = 0; jj < DD; ++jj) {
        int idx = e[u * DD + jj];
        if (idx >= 0) unpack_max(m, *(const uint4*)(X + (size_t)(b * NN + idx) * HH + c8));
    }
#pragma unroll
    for (int i = 0; i < 8; ++i) red[slot][c8 + i] = m[i];
    __syncthreads();
    if (t < HH) {
        float s = 0.f;
#pragma unroll
        for (int k = 0; k < 16; ++k) s += red[k][t];
        partial[((size_t)b * 32 + chunk) * HH + t] = s;
    }
}

__global__ __launch_bounds__(256) void k_sum_final(const float* __restrict__ partial,
                                                   float* __restrict__ out) {
    int g = blockIdx.x * 256 + threadIdx.x;
    int b = g >> 7;
    int c = g & 127;
    float s = 0.f;
#pragma unroll
    for (int k = 0; k < 32; ++k) s += partial[((size_t)b * 32 + k) * HH + c];
    out[g] = s;
}

// ---------------- launcher ----------------
// ws regions:
//   bufH [0, 32M):   h1 (conv1 out, pool1 in) -> h2 (conv2 out, pool_sum in)
//   bufP [32M, 64M): p1 (pool1 out, conv2 in) -> partial (4 MB)
//   meta [64M+):     WT0, WT1, order(640KB), deg, cnt, base_bd, tdeg64  (~67 MB total)

extern "C" void kernel_launch(void* const* d_in, const int* in_sizes, int n_in,
                              void* d_out, int out_size, void* d_ws, size_t ws_size,
                              hipStream_t stream) {
    const float* a  = (const float*)d_in[0];
    const int*   e  = (const int*)d_in[1];
    const float* W0 = (const float*)d_in[2];
    const float* b0 = (const float*)d_in[3];
    const float* W1 = (const float*)d_in[4];
    const float* b1 = (const float*)d_in[5];
    float* out = (float*)d_out;

    char* ws = (char*)d_ws;
    const size_t SB = (size_t)TOTAL * HH * 2;   // 33,554,432
    unsigned short* bufH = (unsigned short*)ws;
    unsigned short* bufP = (unsigned short*)(ws + SB);
    float* partial = (float*)bufP;
    char* dp = ws + 2 * SB;
    unsigned short* WT0 = (unsigned short*)dp;
    unsigned short* WT1 = WT0 + (size_t)ND * HH * 64;
    int* order   = (int*)(WT1 + (size_t)ND * HH * 128);
    int* deg     = order + MAXSG;
    int* cnt     = deg + TOTAL;
    int* base_bd = cnt + BB * 8;
    int* tdeg64  = base_bd + BB * 8;

    hipLaunchKernelGGL(k_hist, dim3(BB), dim3(NN), 0, stream, e, deg, cnt);
    hipLaunchKernelGGL(k_scan_grp, dim3(1), dim3(256), 0, stream, cnt, base_bd, tdeg64);
    hipLaunchKernelGGL(k_init_order, dim3(MAXSG / 512), dim3(512), 0, stream, order);
    hipLaunchKernelGGL(k_scatter, dim3(BB), dim3(NN), 0, stream, deg, base_bd, order);
    hipLaunchKernelGGL(k_prep_wt, dim3(HH, ND), dim3(64), 0, stream, W0, WT0, F_IN, 64);
    hipLaunchKernelGGL(k_prep_wt, dim3(HH, ND), dim3(64), 0, stream, W1, WT1, HH, HH);

    const int lds1 = 16384 + 128 * STG * 2;   // 50176
    const int lds2 = 32768 + 64 * STG * 2;    // 49664

    hipLaunchKernelGGL(k_conv1, dim3(T128), dim3(512), lds1, stream,
                       a, e, WT0, b0, order, tdeg64, bufH);
    hipLaunchKernelGGL(k_pool_bf, dim3(TOTAL / 16), dim3(256), 0, stream, bufH, e, bufP);
    hipLaunchKernelGGL(k_conv2, dim3(T64), dim3(512), lds2, stream,
                       bufP, e, WT1, b1, order, tdeg64, bufH);
    hipLaunchKernelGGL(k_pool_sum_part, dim3(BB * 32), dim3(256), 0, stream, bufH, e, partial);
    hipLaunchKernelGGL(k_sum_final, dim3(BB * HH / 256), dim3(256), 0, stream, partial, out);
}

// Round 14
// 162.243 us; speedup vs baseline: 1.4404x; 1.0174x over previous
//
#include <hip/hip_runtime.h>
#include <math.h>

#define BB 256
#define NN 512
#define DD 6
#define F_IN 62
#define HH 128
#define ND 7
#define TOTAL (BB*NN)      // 131072
#define G8 8               // batches per sort group
#define NG 32              // groups
#define GOPB 5120          // slots per group (4096 + 128-pad headroom, mult of 128)
#define MAXSG (NG*GOPB)    // 163840
#define T128G 40           // 128-row tiles per group
#define T64G 80            // 64-row tiles per group
#define STG 132            // epilogue staging row stride

typedef __bf16 bf16x8 __attribute__((ext_vector_type(8)));
typedef float f32x4 __attribute__((ext_vector_type(4)));

__device__ __forceinline__ unsigned short f2bf(float f) {
    unsigned u = __builtin_bit_cast(unsigned, f);
    u = (u + 0x7FFFu + ((u >> 16) & 1u)) >> 16;
    return (unsigned short)u;
}
__device__ __forceinline__ float lo2f(unsigned x) { return __builtin_bit_cast(float, x << 16); }
__device__ __forceinline__ float hi2f(unsigned x) { return __builtin_bit_cast(float, x & 0xFFFF0000u); }

__device__ __forceinline__ uint4 pack8(const float* s) {
    uint4 r;
    r.x = (unsigned)f2bf(s[0]) | ((unsigned)f2bf(s[1]) << 16);
    r.y = (unsigned)f2bf(s[2]) | ((unsigned)f2bf(s[3]) << 16);
    r.z = (unsigned)f2bf(s[4]) | ((unsigned)f2bf(s[5]) << 16);
    r.w = (unsigned)f2bf(s[6]) | ((unsigned)f2bf(s[7]) << 16);
    return r;
}
__device__ __forceinline__ void unpack_add(float* s, uint4 q) {
    s[0] += lo2f(q.x); s[1] += hi2f(q.x); s[2] += lo2f(q.y); s[3] += hi2f(q.y);
    s[4] += lo2f(q.z); s[5] += hi2f(q.z); s[6] += lo2f(q.w); s[7] += hi2f(q.w);
}
__device__ __forceinline__ void unpack_max(float* s, uint4 q) {
    s[0] = fmaxf(s[0], lo2f(q.x)); s[1] = fmaxf(s[1], hi2f(q.x));
    s[2] = fmaxf(s[2], lo2f(q.y)); s[3] = fmaxf(s[3], hi2f(q.y));
    s[4] = fmaxf(s[4], lo2f(q.z)); s[5] = fmaxf(s[5], hi2f(q.z));
    s[6] = fmaxf(s[6], lo2f(q.w)); s[7] = fmaxf(s[7], hi2f(q.w));
}
__device__ __forceinline__ void rowadd62(float* s, const float* r, int kb) {
    float2 z0 = *(const float2*)(r);     s[0] += z0.x; s[1] += z0.y;
    float2 z1 = *(const float2*)(r + 2); s[2] += z1.x; s[3] += z1.y;
    float2 z2 = *(const float2*)(r + 4); s[4] += z2.x; s[5] += z2.y;
    if (kb < 7) { float2 z3 = *(const float2*)(r + 6); s[6] += z3.x; s[7] += z3.y; }
}

// ---------------- one-kernel group-local degree sort (hist+scan+pad128+scatter) ----------------
// Block = 1 group of 8 batches (4096 nodes). Buckets 128-aligned within the group.

__global__ __launch_bounds__(1024)
void k_sort_grp(const int* __restrict__ e, int* __restrict__ order,
                int* __restrict__ tdeg64) {
    __shared__ int cnt[G8][8];
    __shared__ int base[G8][8];
    __shared__ int bnd[8];
    __shared__ short degl[G8 * NN];
    const int g = blockIdx.x;
    const int t = threadIdx.x;
    if (t < 64) ((int*)cnt)[t] = 0;
    for (int i = t; i < GOPB; i += 1024) order[g * GOPB + i] = -1;
    __syncthreads();
#pragma unroll
    for (int q = 0; q < 4; ++q) {
        const int n = q * 1024 + t;
        const int b8 = n >> 9, nn = n & (NN - 1);
        const int u = (g * G8 + b8) * NN + nn;
        int d = 0;
#pragma unroll
        for (int j = 0; j < DD; ++j) d += (e[u * DD + j] >= 0) ? 1 : 0;
        degl[n] = (short)d;
        atomicAdd(&cnt[b8][d], 1);
    }
    __syncthreads();
    if (t == 0) {
        int acc = g * GOPB;
        for (int d = 0; d < ND; ++d) {
            bnd[d] = acc;
            for (int b8 = 0; b8 < G8; ++b8) { base[b8][d] = acc; acc += cnt[b8][d]; }
            acc = (acc + 127) & ~127;
        }
        bnd[7] = acc;
    }
    __syncthreads();
    for (int i = t; i < T64G; i += 1024) {
        const int s = g * GOPB + i * 64;
        int dd = 0;
        if (s < bnd[7]) {
            for (int d = ND - 1; d >= 0; --d) if (s >= bnd[d]) { dd = d; break; }
        }
        tdeg64[g * T64G + i] = dd;
    }
    __syncthreads();
#pragma unroll
    for (int q = 0; q < 4; ++q) {
        const int n = q * 1024 + t;
        const int b8 = n >> 9, nn = n & (NN - 1);
        const int slot = atomicAdd(&base[b8][degl[n]], 1);
        order[slot] = (g * G8 + b8) * NN + nn;
    }
}

// ---------------- prep: both weights -> WT [ND][HH][K] bf16 (K-contig, zero-pad) --------------

__global__ void k_prep_w2(const float* __restrict__ W0, unsigned short* __restrict__ WT0,
                          const float* __restrict__ W1, unsigned short* __restrict__ WT1) {
    const int n = blockIdx.x;
    const int d = blockIdx.y;
    for (int k = threadIdx.x; k < 64; k += 64) {
        float v = (k < F_IN) ? W0[((size_t)d * F_IN + k) * HH + n] : 0.f;
        WT0[((size_t)d * HH + n) * 64 + k] = f2bf(v);
    }
    for (int k = threadIdx.x; k < 128; k += 64)
        WT1[((size_t)d * HH + n) * 128 + k] = f2bf(W1[((size_t)d * HH + k) * HH + n]);
}

// ---------------- gather1: S1[slot][0..64) = a[v] + sum(a[nbr]) — streaming, group-local -------

__global__ __launch_bounds__(512)
void k_gather1(const float* __restrict__ a, const int* __restrict__ e,
               const int* __restrict__ order, unsigned short* __restrict__ S1) {
    const int bi = blockIdx.x;                   // 2560 = 8 xcd x 320
    const int x8 = bi & 7;
    const int r = bi >> 3;                       // 0..319
    const int g = x8 * 4 + r / 80;
    const int blk = r % 80;                      // 64 slots x 8 kb per block
    const int slot = g * GOPB + blk * 64 + (threadIdx.x >> 3);
    const int kb = threadIdx.x & 7;
    const int v = order[slot];
    if (v < 0) return;
    const int* ep = e + (size_t)v * DD;
    const int nb = v & ~(NN - 1);
    float s[8] = {0.f, 0.f, 0.f, 0.f, 0.f, 0.f, 0.f, 0.f};
    rowadd62(s, a + (size_t)v * F_IN + kb * 8, kb);
#pragma unroll
    for (int jj = 0; jj < DD; ++jj) {
        int idx = ep[jj];
        if (idx >= 0) rowadd62(s, a + (size_t)(nb + idx) * F_IN + kb * 8, kb);
    }
    *(uint4*)(S1 + (size_t)slot * 64 + kb * 8) = pack8(s);
}

// ---------------- gather2: S2[slot][0..128) = p1[v] + sum(p1[nbr]) — streaming, group-local ----

__global__ __launch_bounds__(512)
void k_gather2(const unsigned short* __restrict__ P1, const int* __restrict__ e,
               const int* __restrict__ order, unsigned short* __restrict__ S2) {
    const int bi = blockIdx.x;                   // 5120 = 8 xcd x 640
    const int x8 = bi & 7;
    const int r = bi >> 3;                       // 0..639
    const int g = x8 * 4 + r / 160;
    const int blk = r % 160;                     // 32 slots x 16 kb per block
    const int slot = g * GOPB + blk * 32 + (threadIdx.x >> 4);
    const int kb = threadIdx.x & 15;
    const int v = order[slot];
    if (v < 0) return;
    const int* ep = e + (size_t)v * DD;
    const int nb = v & ~(NN - 1);
    const unsigned short* base = P1 + kb * 8;
    float s[8] = {0.f, 0.f, 0.f, 0.f, 0.f, 0.f, 0.f, 0.f};
    unpack_add(s, *(const uint4*)(base + (size_t)v * HH));
#pragma unroll
    for (int jj = 0; jj < DD; ++jj) {
        int idx = ep[jj];
        if (idx >= 0) unpack_add(s, *(const uint4*)(base + (size_t)(nb + idx) * HH));
    }
    *(uint4*)(S2 + (size_t)slot * HH + kb * 8) = pack8(s);
}

// ---------------- gemm1: 128-row degree-pure tile, K=64, W[d] in LDS, scatter-store natural ----

__global__ __launch_bounds__(512, 6)
void k_gemm1(const unsigned short* __restrict__ S,
             const unsigned short* __restrict__ WT, const float* __restrict__ bias,
             const int* __restrict__ order, const int* __restrict__ tdeg64,
             unsigned short* __restrict__ Y) {
    extern __shared__ char smem[];
    unsigned short* Wl  = (unsigned short*)smem;            // 16 KB
    unsigned short* stg = (unsigned short*)(smem + 16384);  // 33792 B
    __shared__ int vT[128];

    const int t = threadIdx.x;
    const int l = t & 63;
    const int w = t >> 6;
    const int lr = l & 15;
    const int lq = l >> 4;

    const int bi = blockIdx.x;                   // 1280 = 8 x 160
    const int x8 = bi & 7;
    const int r = bi >> 3;
    const int g = x8 * 4 + r / T128G;
    const int ti = r % T128G;
    const int sbase = g * GOPB + ti * 128;
    if (order[sbase] < 0) return;
    const int d = tdeg64[g * T64G + ti * 2];

    if (t < 128) vT[t] = order[sbase + t];

    // A fragments straight from sorted S (issued before W barrier)
    const unsigned short* sp = S + (size_t)(sbase + w * 16 + lr) * 64;
    bf16x8 af0 = *(const bf16x8*)(sp + lq * 8);
    bf16x8 af1 = *(const bf16x8*)(sp + (lq + 4) * 8);

    for (int u = t; u < 1024; u += 512) {        // W[d]: 128 cols x 8 kb, swizzled
        const int col = u >> 3, kb = u & 7;
        *(uint4*)&Wl[(col * 8 + (kb ^ (col & 7))) * 8] =
            *(const uint4*)(WT + ((size_t)d * HH + col) * 64 + kb * 8);
    }
    __syncthreads();

    f32x4 acc[8];
#pragma unroll
    for (int fr = 0; fr < 8; ++fr) {
        const int col = fr * 16 + lr;
        f32x4 z = {0.f, 0.f, 0.f, 0.f};
        bf16x8 b0 = *(const bf16x8*)&Wl[(col * 8 + ((0 + lq) ^ (col & 7))) * 8];
        z = __builtin_amdgcn_mfma_f32_16x16x32_bf16(af0, b0, z, 0, 0, 0);
        bf16x8 b1 = *(const bf16x8*)&Wl[(col * 8 + ((4 + lq) ^ (col & 7))) * 8];
        z = __builtin_amdgcn_mfma_f32_16x16x32_bf16(af1, b1, z, 0, 0, 0);
        acc[fr] = z;
    }

    __syncthreads();
#pragma unroll
    for (int fr = 0; fr < 8; ++fr) {
        const int col = fr * 16 + lr;
        const float bv = bias[d * HH + col];
#pragma unroll
        for (int r2 = 0; r2 < 4; ++r2) {
            float zz = 1.f / (1.f + __expf(-(acc[fr][r2] + bv)));
            stg[(w * 16 + lq * 4 + r2) * STG + col] = f2bf(zz);
        }
    }
    __syncthreads();
    for (int u = t; u < 2048; u += 512) {
        const int n = u >> 4, c8 = (u & 15) * 8;
        const int v = vT[n];
        if (v >= 0)
            *(uint4*)&Y[(size_t)v * HH + c8] = *(const uint4*)&stg[n * STG + c8];
    }
}

// ---------------- gemm2: 64-row degree-pure tile, K=128, W[d] in LDS, scatter-store natural ----

__global__ __launch_bounds__(512, 6)
void k_gemm2(const unsigned short* __restrict__ S,
             const unsigned short* __restrict__ WT, const float* __restrict__ bias,
             const int* __restrict__ order, const int* __restrict__ tdeg64,
             unsigned short* __restrict__ Y) {
    extern __shared__ char smem[];
    unsigned short* Wl  = (unsigned short*)smem;            // 32 KB
    unsigned short* stg = (unsigned short*)(smem + 32768);  // 16896 B
    __shared__ int vT[64];

    const int t = threadIdx.x;
    const int l = t & 63;
    const int w = t >> 6;
    const int lr = l & 15;
    const int lq = l >> 4;

    const int bi = blockIdx.x;                   // 2560 = 8 x 320
    const int x8 = bi & 7;
    const int r = bi >> 3;
    const int g = x8 * 4 + r / T64G;
    const int ti = r % T64G;
    const int sbase = g * GOPB + ti * 64;
    if (order[sbase] < 0) return;
    const int d = tdeg64[g * T64G + ti];

    if (t < 64) vT[t] = order[sbase + t];

    const int nrow = (w & 3) * 16 + lr;
    const int ch = w >> 2;

    // A fragments straight from sorted S (issued before W barrier)
    const unsigned short* sp = S + (size_t)(sbase + nrow) * 128;
    bf16x8 af[4];
#pragma unroll
    for (int kk = 0; kk < 4; ++kk)
        af[kk] = *(const bf16x8*)(sp + (lq + 4 * kk) * 8);

    for (int u = t; u < 2048; u += 512) {        // W[d]: 128 cols x 16 kb, swizzled
        const int col = u >> 4, kb = u & 15;
        *(uint4*)&Wl[(col * 16 + (kb ^ (col & 7))) * 8] =
            *(const uint4*)(WT + ((size_t)d * HH + col) * 128 + kb * 8);
    }
    __syncthreads();

    f32x4 acc[4];
#pragma unroll
    for (int fr = 0; fr < 4; ++fr) {
        const int col = ch * 64 + fr * 16 + lr;
        f32x4 z = {0.f, 0.f, 0.f, 0.f};
#pragma unroll
        for (int kk = 0; kk < 4; ++kk) {
            bf16x8 bfr = *(const bf16x8*)&Wl[(col * 16 + ((4 * kk + lq) ^ (col & 7))) * 8];
            z = __builtin_amdgcn_mfma_f32_16x16x32_bf16(af[kk], bfr, z, 0, 0, 0);
        }
        acc[fr] = z;
    }

    __syncthreads();
#pragma unroll
    for (int fr = 0; fr < 4; ++fr) {
        const int col = ch * 64 + fr * 16 + lr;
        const float bv = bias[d * HH + col];
#pragma unroll
        for (int r2 = 0; r2 < 4; ++r2) {
            float zz = 1.f / (1.f + __expf(-(acc[fr][r2] + bv)));
            stg[((w & 3) * 16 + lq * 4 + r2) * STG + col] = f2bf(zz);
        }
    }
    __syncthreads();
    for (int u = t; u < 1024; u += 512) {
        const int n = u >> 4, c8 = (u & 15) * 8;
        const int v = vT[n];
        if (v >= 0)
            *(uint4*)&Y[(size_t)v * HH + c8] = *(const uint4*)&stg[n * STG + c8];
    }
}

// ---------------- pool1: natural in/out, batch-local ----------------

__global__ __launch_bounds__(256) void k_pool_bf(const unsigned short* __restrict__ X,
                                                 const int* __restrict__ e,
                                                 unsigned short* __restrict__ P) {
    const int t = threadIdx.x;
    const int u = blockIdx.x * 16 + (t >> 4);
    const int c8 = (t & 15) * 8;
    const int nb = u & ~(NN - 1);
    float m[8];
    {
        uint4 p = *(const uint4*)(X + (size_t)u * HH + c8);
        m[0] = lo2f(p.x); m[1] = hi2f(p.x); m[2] = lo2f(p.y); m[3] = hi2f(p.y);
        m[4] = lo2f(p.z); m[5] = hi2f(p.z); m[6] = lo2f(p.w); m[7] = hi2f(p.w);
    }
#pragma unroll
    for (int jj = 0; jj < DD; ++jj) {
        int idx = e[u * DD + jj];
        if (idx >= 0) unpack_max(m, *(const uint4*)(X + (size_t)(nb + idx) * HH + c8));
    }
    *(uint4*)&P[(size_t)u * HH + c8] = pack8(m);
}

// ---------------- final: pool (natural) + partial sum (32 blocks/batch) ------------------------

__global__ __launch_bounds__(256) void k_pool_sum_part(const unsigned short* __restrict__ X,
                                                       const int* __restrict__ e,
                                                       float* __restrict__ partial) {
    __shared__ float red[16][HH + 4];
    const int t = threadIdx.x;
    const int b = blockIdx.x >> 5;
    const int chunk = blockIdx.x & 31;
    const int slot = t >> 4;
    const int c8 = (t & 15) * 8;

    const int u = b * NN + chunk * 16 + slot;
    float m[8];
    {
        uint4 p = *(const uint4*)(X + (size_t)u * HH + c8);
        m[0] = lo2f(p.x); m[1] = hi2f(p.x); m[2] = lo2f(p.y); m[3] = hi2f(p.y);
        m[4] = lo2f(p.z); m[5] = hi2f(p.z); m[6] = lo2f(p.w); m[7] = hi2f(p.w);
    }
#pragma unroll
    for (int jj = 0; jj < DD; ++jj) {
        int idx = e[u * DD + jj];
        if (idx >= 0) unpack_max(m, *(const uint4*)(X + (size_t)(b * NN + idx) * HH + c8));
    }
#pragma unroll
    for (int i = 0; i < 8; ++i) red[slot][c8 + i] = m[i];
    __syncthreads();
    if (t < HH) {
        float s = 0.f;
#pragma unroll
        for (int k = 0; k < 16; ++k) s += red[k][t];
        partial[((size_t)b * 32 + chunk) * HH + t] = s;
    }
}

__global__ __launch_bounds__(256) void k_sum_final(const float* __restrict__ partial,
                                                   float* __restrict__ out) {
    int gi = blockIdx.x * 256 + threadIdx.x;
    int b = gi >> 7;
    int c = gi & 127;
    float s = 0.f;
#pragma unroll
    for (int k = 0; k < 32; ++k) s += partial[((size_t)b * 32 + k) * HH + c];
    out[gi] = s;
}

// ---------------- launcher ----------------
// ws overlays (bytes; lifetimes disjoint):
//   S1 [0, 21.0M)       gather1 -> gemm1
//   h1 [21.0M, 54.5M)   gemm1 -> pool1
//   p1 [54.5M, 88.1M)   pool1 -> gather2
//   S2 [0, 41.9M)       gather2 -> gemm2        (overlays dead S1+h1)
//   h2 [41.9M, 75.5M)   gemm2 -> pool_sum       (overlays dead h1-tail+p1-head)
//   partial [0, 4M)     pool_sum -> sum_final   (overlays dead S2-head)
//   meta [88.1M+)       WT0, WT1, order, tdeg64 (~89 MB total)

extern "C" void kernel_launch(void* const* d_in, const int* in_sizes, int n_in,
                              void* d_out, int out_size, void* d_ws, size_t ws_size,
                              hipStream_t stream) {
    const float* a  = (const float*)d_in[0];
    const int*   e  = (const int*)d_in[1];
    const float* W0 = (const float*)d_in[2];
    const float* b0 = (const float*)d_in[3];
    const float* W1 = (const float*)d_in[4];
    const float* b1 = (const float*)d_in[5];
    float* out = (float*)d_out;

    char* ws = (char*)d_ws;
    unsigned short* S1 = (unsigned short*)ws;
    unsigned short* h1 = (unsigned short*)(ws + 20971520);
    unsigned short* p1 = (unsigned short*)(ws + 54525952);
    unsigned short* S2 = (unsigned short*)ws;
    unsigned short* h2 = (unsigned short*)(ws + 41943040);
    float* partial = (float*)ws;
    char* dp = ws + 88080384;
    unsigned short* WT0 = (unsigned short*)dp;
    unsigned short* WT1 = WT0 + (size_t)ND * HH * 64;
    int* order  = (int*)(WT1 + (size_t)ND * HH * 128);
    int* tdeg64 = order + MAXSG;

    hipLaunchKernelGGL(k_sort_grp, dim3(NG), dim3(1024), 0, stream, e, order, tdeg64);
    hipLaunchKernelGGL(k_prep_w2, dim3(HH, ND), dim3(64), 0, stream, W0, WT0, W1, WT1);

    const int lds1 = 16384 + 128 * STG * 2;   // 50176
    const int lds2 = 32768 + 64 * STG * 2;    // 49664

    hipLaunchKernelGGL(k_gather1, dim3(NG * 80), dim3(512), 0, stream, a, e, order, S1);
    hipLaunchKernelGGL(k_gemm1, dim3(NG * T128G), dim3(512), lds1, stream,
                       S1, WT0, b0, order, tdeg64, h1);
    hipLaunchKernelGGL(k_pool_bf, dim3(TOTAL / 16), dim3(256), 0, stream, h1, e, p1);
    hipLaunchKernelGGL(k_gather2, dim3(NG * 160), dim3(512), 0, stream, p1, e, order, S2);
    hipLaunchKernelGGL(k_gemm2, dim3(NG * T64G), dim3(512), lds2, stream,
                       S2, WT1, b1, order, tdeg64, h2);
    hipLaunchKernelGGL(k_pool_sum_part, dim3(BB * 32), dim3(256), 0, stream, h2, e, partial);
    hipLaunchKernelGGL(k_sum_final, dim3(BB * HH / 256), dim3(256), 0, stream, partial, out);
}